// Round 1
// baseline (1112.238 us; speedup 1.0000x reference)
//
#include <hip/hip_runtime.h>
#include <hip/hip_fp16.h>

typedef _Float16 f16;
typedef __attribute__((ext_vector_type(8))) _Float16 f16x8;
typedef __attribute__((ext_vector_type(4))) float f32x4;

#define MFMA16 __builtin_amdgcn_mfma_f32_16x16x32_f16

// ---------------- rpb gather: rpb16[h][n][m] = table[rel[n,m]][h] ----------------
__global__ __launch_bounds__(256) void rpb_build_k(const float* __restrict__ tab,
                                                   const int* __restrict__ rel,
                                                   f16* __restrict__ out) {
  int i = blockIdx.x * 256 + threadIdx.x;
  if (i >= 196 * 196) return;
  int idx = rel[i];
#pragma unroll
  for (int h = 0; h < 12; ++h)
    out[h * (196 * 196) + i] = (f16)tab[idx * 12 + h];
}

// ---------------- GEMM: MODE 0 = qkv (A fp32), MODE 1 = proj (A fp16) ------------
// C = A[M,768] @ W[N,768]^T  ; 128x128 tile, BK=32, 4 waves (2x2), 16x16x32 f16 MFMA
template <int MODE>
__global__ __launch_bounds__(256) void gemm_k(
    const void* __restrict__ Ain, const float* __restrict__ W,
    const float* __restrict__ bias_a, const float* __restrict__ bias_b,
    f16* __restrict__ q_out, f16* __restrict__ k_out, f16* __restrict__ vT_out,
    float* __restrict__ f_out) {
  constexpr int NTIL = (MODE == 0) ? 18 : 6;  // 2304/128 or 768/128
  constexpr int KT = 24;                      // 768/32

  __shared__ f16x8 As[2][4][128];  // [buf][k-chunk g][row m] ; chunk = 8 fp16 = 16B
  __shared__ f16x8 Bs[2][4][128];

  const int tid = threadIdx.x;
  const int bid = blockIdx.x;
  const int bcol = bid % NTIL, brow = bid / NTIL;
  const int lane = tid & 63, wid = tid >> 6;
  const int wrow = wid >> 1, wcol = wid & 1;
  const int l15 = lane & 15, g4 = lane >> 4;

  const int m0 = tid >> 2, g0 = tid & 3;  // staging: 2 chunks/thread/matrix
  const int m1 = m0 + 64;

  const float* Af = (const float*)Ain;
  const f16* Ah = (const f16*)Ain;

  float4 ra[2][2], rb[2][2];
  f16x8 ra16[2];

  auto issueLoads = [&](int kt) {
    if constexpr (MODE == 0) {
      const float* p0 = Af + (size_t)(brow * 128 + m0) * 768 + kt * 32 + g0 * 8;
      const float* p1 = Af + (size_t)(brow * 128 + m1) * 768 + kt * 32 + g0 * 8;
      ra[0][0] = ((const float4*)p0)[0]; ra[0][1] = ((const float4*)p0)[1];
      ra[1][0] = ((const float4*)p1)[0]; ra[1][1] = ((const float4*)p1)[1];
    } else {
      ra16[0] = *(const f16x8*)(Ah + (size_t)(brow * 128 + m0) * 768 + kt * 32 + g0 * 8);
      ra16[1] = *(const f16x8*)(Ah + (size_t)(brow * 128 + m1) * 768 + kt * 32 + g0 * 8);
    }
    const float* w0 = W + (size_t)(bcol * 128 + m0) * 768 + kt * 32 + g0 * 8;
    const float* w1 = W + (size_t)(bcol * 128 + m1) * 768 + kt * 32 + g0 * 8;
    rb[0][0] = ((const float4*)w0)[0]; rb[0][1] = ((const float4*)w0)[1];
    rb[1][0] = ((const float4*)w1)[0]; rb[1][1] = ((const float4*)w1)[1];
  };

  auto writeLds = [&](int buf) {
#pragma unroll
    for (int i = 0; i < 2; ++i) {
      const int m = (i == 0) ? m0 : m1;
      f16x8 ha, hb;
      if constexpr (MODE == 0) {
#pragma unroll
        for (int j = 0; j < 4; ++j) {
          ha[j] = (f16)((&ra[i][0].x)[j]);
          ha[4 + j] = (f16)((&ra[i][1].x)[j]);
        }
      } else {
        ha = ra16[i];
      }
#pragma unroll
      for (int j = 0; j < 4; ++j) {
        hb[j] = (f16)((&rb[i][0].x)[j]);
        hb[4 + j] = (f16)((&rb[i][1].x)[j]);
      }
      As[buf][g0][m] = ha;
      Bs[buf][g0][m] = hb;
    }
  };

  const f32x4 zero4 = {0.f, 0.f, 0.f, 0.f};
  f32x4 acc[4][4];
#pragma unroll
  for (int i = 0; i < 4; ++i)
#pragma unroll
    for (int j = 0; j < 4; ++j) acc[i][j] = zero4;

  issueLoads(0);
  writeLds(0);
  __syncthreads();

  for (int kt = 0; kt < KT; ++kt) {
    const int cur = kt & 1;
    if (kt + 1 < KT) issueLoads(kt + 1);
    f16x8 af[4], bf[4];
#pragma unroll
    for (int f = 0; f < 4; ++f) {
      af[f] = As[cur][g4][wrow * 64 + f * 16 + l15];
      bf[f] = Bs[cur][g4][wcol * 64 + f * 16 + l15];
    }
#pragma unroll
    for (int i = 0; i < 4; ++i)
#pragma unroll
      for (int j = 0; j < 4; ++j)
        acc[i][j] = MFMA16(af[i], bf[j], acc[i][j], 0, 0, 0);
    if (kt + 1 < KT) writeLds(cur ^ 1);
    __syncthreads();
  }

  // ---- epilogue ----
  if constexpr (MODE == 0) {
    const int s = bcol / 6;  // 0=q, 1=k, 2=v  (each 6 col-tiles of 128)
#pragma unroll
    for (int i = 0; i < 4; ++i) {
#pragma unroll
      for (int r = 0; r < 4; ++r) {
        const int row = brow * 128 + wrow * 64 + i * 16 + g4 * 4 + r;
        const int bI = row / 196;
        const int nI = row - bI * 196;
#pragma unroll
        for (int j = 0; j < 4; ++j) {
          const int col = bcol * 128 + wcol * 64 + j * 16 + l15;
          const int rem = col - s * 768;
          const int hh = rem >> 6, dd = rem & 63;
          float v = acc[i][j][r];
          if (s == 0) {
            v = (v + bias_a[rem]) * 0.125f;
            q_out[(((size_t)bI * 12 + hh) * 196 + nI) * 64 + dd] = (f16)v;
          } else if (s == 1) {
            k_out[(((size_t)bI * 12 + hh) * 196 + nI) * 64 + dd] = (f16)v;
          } else {
            v += bias_b[rem];
            vT_out[(((size_t)bI * 12 + hh) * 64 + dd) * 224 + nI] = (f16)v;
          }
        }
      }
    }
  } else {
#pragma unroll
    for (int i = 0; i < 4; ++i) {
#pragma unroll
      for (int r = 0; r < 4; ++r) {
        const int row = brow * 128 + wrow * 64 + i * 16 + g4 * 4 + r;
        float* orow = f_out + (size_t)row * 768;
#pragma unroll
        for (int j = 0; j < 4; ++j) {
          const int col = bcol * 128 + wcol * 64 + j * 16 + l15;
          orow[col] = acc[i][j][r] + bias_a[col];
        }
      }
    }
  }
}

// ---------------- fused window attention: one WG (4 waves) per (b,h) -------------
__global__ __launch_bounds__(256) void attn_k(const f16* __restrict__ qg,
                                              const f16* __restrict__ kg,
                                              const f16* __restrict__ vTg,
                                              const f16* __restrict__ rpb,
                                              f16* __restrict__ og) {
  extern __shared__ char smem[];
  f16x8* Klds = (f16x8*)smem;              // [208 rows][8 chunks], swizzled
  f16x8* Vlds = (f16x8*)(smem + 26624);    // [64 d][32 m-chunks], swizzled
  f16x8* Plds = (f16x8*)(smem + 59392);    // 4 waves x [16 n][32 m-chunks]

  const int tid = threadIdx.x;
  const int bh = blockIdx.x;
  const int b = bh / 12, h = bh - b * 12;
  const int lane = tid & 63, wid = tid >> 6;
  const int l15 = lane & 15, g4 = lane >> 4;

  f16x8 z8;
#pragma unroll
  for (int j = 0; j < 8; ++j) z8[j] = (f16)0.f;

  // stage K [196][64] -> chunk layout [m][dc ^ (m&7)]
  const f16* kgb = kg + (size_t)bh * (196 * 64);
  for (int c = tid; c < 196 * 8; c += 256) {
    int m = c >> 3, dc = c & 7;
    Klds[m * 8 + (dc ^ (m & 7))] = *(const f16x8*)(kgb + m * 64 + dc * 8);
  }
  // stage V^T [64][224] -> [d][mc ^ (d&7)], zero-fill m >= 196
  const f16* vgb = vTg + (size_t)bh * (64 * 224);
  for (int c = tid; c < 64 * 32; c += 256) {
    int d = c >> 5, mc = c & 31;
    f16x8 v;
    if (mc < 24) {
      v = *(const f16x8*)(vgb + d * 224 + mc * 8);
    } else if (mc == 24) {
      v = *(const f16x8*)(vgb + d * 224 + mc * 8);
#pragma unroll
      for (int j = 4; j < 8; ++j) v[j] = (f16)0.f;  // cols 196..199
    } else {
      v = z8;
    }
    Vlds[d * 32 + (mc ^ (d & 7))] = v;
  }
  // zero the P pad chunks that PV reads but softmax never writes (m in [208,224))
  f16x8* Pw = Plds + wid * (16 * 32);
  if (g4 < 2) {
    int n = l15;
    Pw[n * 32 + ((26 + g4) ^ (n & 7))] = z8;
  }
  __syncthreads();

  const f16* qgb = qg + (size_t)bh * (196 * 64);
  const f16* rpbh = rpb + (size_t)h * (196 * 196);

  for (int rt = wid; rt < 13; rt += 4) {
    const int n0 = rt * 16;
    f16x8 qf0 = *(const f16x8*)(qgb + (n0 + l15) * 64 + g4 * 8);
    f16x8 qf1 = *(const f16x8*)(qgb + (n0 + l15) * 64 + 32 + g4 * 8);

    // prefetch rpb (clamped indices, always in-bounds; invalid masked later)
    float rv[13][4];
#pragma unroll
    for (int mt = 0; mt < 13; ++mt) {
      const int m = mt * 16 + l15;
      const int mcl = (m < 196) ? m : 195;
#pragma unroll
      for (int r = 0; r < 4; ++r) {
        const int n = n0 + g4 * 4 + r;
        const int ncl = (n < 196) ? n : 195;
        rv[mt][r] = (float)rpbh[ncl * 196 + mcl];
      }
    }

    // S = Q K^T  (rows n, cols m)
    const f32x4 zero4 = {0.f, 0.f, 0.f, 0.f};
    f32x4 s[13];
#pragma unroll
    for (int mt = 0; mt < 13; ++mt) {
      const int m = mt * 16 + l15;
      f16x8 k0 = Klds[m * 8 + ((g4) ^ (m & 7))];
      f16x8 k1 = Klds[m * 8 + ((4 + g4) ^ (m & 7))];
      s[mt] = MFMA16(qf0, k0, zero4, 0, 0, 0);
      s[mt] = MFMA16(qf1, k1, s[mt], 0, 0, 0);
    }

    // + rpb, mask, softmax (rows live across 16-lane groups; reduce over l&15)
    float mx[4] = {-3e38f, -3e38f, -3e38f, -3e38f};
#pragma unroll
    for (int mt = 0; mt < 13; ++mt) {
      const int m = mt * 16 + l15;
#pragma unroll
      for (int r = 0; r < 4; ++r) {
        const int n = n0 + g4 * 4 + r;
        float v = (m < 196 && n < 196) ? s[mt][r] + rv[mt][r] : -1e30f;
        s[mt][r] = v;
        mx[r] = fmaxf(mx[r], v);
      }
    }
#pragma unroll
    for (int r = 0; r < 4; ++r) {
      mx[r] = fmaxf(mx[r], __shfl_xor(mx[r], 1));
      mx[r] = fmaxf(mx[r], __shfl_xor(mx[r], 2));
      mx[r] = fmaxf(mx[r], __shfl_xor(mx[r], 4));
      mx[r] = fmaxf(mx[r], __shfl_xor(mx[r], 8));
    }
    float sm[4] = {0.f, 0.f, 0.f, 0.f};
#pragma unroll
    for (int mt = 0; mt < 13; ++mt)
#pragma unroll
      for (int r = 0; r < 4; ++r) {
        float p = __expf(s[mt][r] - mx[r]);
        s[mt][r] = p;
        sm[r] += p;
      }
#pragma unroll
    for (int r = 0; r < 4; ++r) {
      sm[r] += __shfl_xor(sm[r], 1);
      sm[r] += __shfl_xor(sm[r], 2);
      sm[r] += __shfl_xor(sm[r], 4);
      sm[r] += __shfl_xor(sm[r], 8);
    }
    float rinv[4];
#pragma unroll
    for (int r = 0; r < 4; ++r) rinv[r] = 1.f / sm[r];

    // write P (fp16) into wave-private swizzled LDS
#pragma unroll
    for (int mt = 0; mt < 13; ++mt) {
      const int m = mt * 16 + l15;
#pragma unroll
      for (int r = 0; r < 4; ++r) {
        const int n = g4 * 4 + r;  // local row
        f16* dst = (f16*)Pw + n * 256 + (((m >> 3) ^ (n & 7)) << 3) + (m & 7);
        *dst = (f16)s[mt][r];
      }
    }

    // O = P V   (A-frag rows n = l&15 from Pw; B-frags from Vlds)
    f32x4 o[4];
#pragma unroll
    for (int dt = 0; dt < 4; ++dt) o[dt] = zero4;
#pragma unroll
    for (int ks = 0; ks < 7; ++ks) {
      f16x8 pa = Pw[l15 * 32 + ((ks * 4 + g4) ^ (l15 & 7))];
#pragma unroll
      for (int dt = 0; dt < 4; ++dt) {
        const int d = dt * 16 + l15;
        f16x8 vf = Vlds[d * 32 + ((ks * 4 + g4) ^ (d & 7))];
        o[dt] = MFMA16(pa, vf, o[dt], 0, 0, 0);
      }
    }

    // write attention output [b][n][h*64+d] fp16
#pragma unroll
    for (int r = 0; r < 4; ++r) {
      const int n = n0 + g4 * 4 + r;
      if (n < 196) {
        f16* orow = og + ((size_t)b * 196 + n) * 768 + h * 64;
#pragma unroll
        for (int dt = 0; dt < 4; ++dt)
          orow[dt * 16 + l15] = (f16)(o[dt][r] * rinv[r]);
      }
    }
  }
}

// ------------------------------- launcher ---------------------------------------
extern "C" void kernel_launch(void* const* d_in, const int* in_sizes, int n_in,
                              void* d_out, int out_size, void* d_ws, size_t ws_size,
                              hipStream_t stream) {
  const float* x = (const float*)d_in[0];
  const float* qkv_w = (const float*)d_in[1];
  const float* q_bias = (const float*)d_in[2];
  const float* v_bias = (const float*)d_in[3];
  const float* rpb_tab = (const float*)d_in[4];
  const float* proj_w = (const float*)d_in[5];
  const float* proj_b = (const float*)d_in[6];
  const int* rel = (const int*)d_in[7];
  float* out = (float*)d_out;

  // workspace layout (bytes)
  const size_t SZ_Q = 77070336;   // [3072][196][64] f16
  const size_t SZ_K = 77070336;
  const size_t SZ_VT = 88080384;  // [3072][64][224] f16
  const size_t SZ_AO = 77070336;  // [50176][768] f16
  const size_t SZ_RP = 921984;    // [12][196][196] f16
  if (ws_size < SZ_Q + SZ_K + SZ_VT + SZ_AO + SZ_RP) return;

  char* w = (char*)d_ws;
  f16* q_ = (f16*)w;
  f16* k_ = (f16*)(w + SZ_Q);
  f16* vT_ = (f16*)(w + SZ_Q + SZ_K);
  f16* ao_ = (f16*)(w + SZ_Q + SZ_K + SZ_VT);
  f16* rp_ = (f16*)(w + SZ_Q + SZ_K + SZ_VT + SZ_AO);

  (void)hipFuncSetAttribute((const void*)attn_k,
                            hipFuncAttributeMaxDynamicSharedMemorySize, 92160);

  rpb_build_k<<<(196 * 196 + 255) / 256, 256, 0, stream>>>(rpb_tab, rel, rp_);
  gemm_k<0><<<392 * 18, 256, 0, stream>>>(x, qkv_w, q_bias, v_bias,
                                          q_, k_, vT_, nullptr);
  attn_k<<<3072, 256, 92160, stream>>>(q_, k_, vT_, rp_, ao_);
  gemm_k<1><<<392 * 6, 256, 0, stream>>>(ao_, proj_w, proj_b, nullptr,
                                         nullptr, nullptr, nullptr, out);
}

// Round 2
// 822.521 us; speedup vs baseline: 1.3522x; 1.3522x over previous
//
#include <hip/hip_runtime.h>
#include <hip/hip_fp16.h>

typedef _Float16 f16;
typedef __attribute__((ext_vector_type(8))) _Float16 f16x8;
typedef __attribute__((ext_vector_type(4))) float f32x4;

#define MFMA16 __builtin_amdgcn_mfma_f32_16x16x32_f16

__device__ __forceinline__ void gload16(const f16* g, char* l) {
  __builtin_amdgcn_global_load_lds(
      (const __attribute__((address_space(1))) void*)g,
      (__attribute__((address_space(3))) void*)l, 16, 0, 0);
}

// ---------------- fp32 -> fp16 bulk convert (8 elem / thread / iter) -------------
__global__ __launch_bounds__(256) void cvt_k(const float* __restrict__ in,
                                             f16* __restrict__ out, int n8) {
  int i = blockIdx.x * 256 + threadIdx.x;
  const int stride = gridDim.x * 256;
  for (; i < n8; i += stride) {
    const float4* p = (const float4*)(in + (size_t)i * 8);
    float4 a = p[0], b = p[1];
    f16x8 h;
    h[0] = (f16)a.x; h[1] = (f16)a.y; h[2] = (f16)a.z; h[3] = (f16)a.w;
    h[4] = (f16)b.x; h[5] = (f16)b.y; h[6] = (f16)b.z; h[7] = (f16)b.w;
    *(f16x8*)(out + (size_t)i * 8) = h;
  }
}

// ---------------- rpb gather: rpb16[h][n][m] = table[rel[n,m]][h] ----------------
__global__ __launch_bounds__(256) void rpb_build_k(const float* __restrict__ tab,
                                                   const int* __restrict__ rel,
                                                   f16* __restrict__ out) {
  int i = blockIdx.x * 256 + threadIdx.x;
  if (i >= 196 * 196) return;
  int idx = rel[i];
#pragma unroll
  for (int h = 0; h < 12; ++h)
    out[h * (196 * 196) + i] = (f16)tab[idx * 12 + h];
}

// ---------------- GEMM: C = A[M,768] @ W[N,768]^T, fp16 in, 128x128 tile ---------
// MODE 0 = qkv epilogue (scatter q/k/vT fp16), MODE 1 = proj epilogue (fp32+bias)
// global_load_lds staging, swizzled LDS [row][chunk^(row&7)], XCD-swizzled grid.
template <int MODE>
__global__ __launch_bounds__(256) void gemm_k(
    const f16* __restrict__ A, const f16* __restrict__ W,
    const float* __restrict__ bias_a, const float* __restrict__ bias_b,
    f16* __restrict__ q_out, f16* __restrict__ k_out, f16* __restrict__ vT_out,
    float* __restrict__ f_out) {
  constexpr int NTIL = (MODE == 0) ? 18 : 6;   // 2304/128 or 768/128
  constexpr int CPX = (MODE == 0) ? 882 : 294; // grid / 8 XCDs
  constexpr int KT = 12;                       // 768 / 64

  __shared__ char lds[32768];  // As 16KB | Bs 16KB ; row = 128B, swizzled chunks
  char* Asb = lds;
  char* Bsb = lds + 16384;

  const int tid = threadIdx.x;
  const int lbid = (blockIdx.x & 7) * CPX + (blockIdx.x >> 3);
  const int bcol = lbid % NTIL, brow = lbid / NTIL;
  const int lane = tid & 63, wid = tid >> 6;
  const int wrow = wid >> 1, wcol = wid & 1;
  const int l15 = lane & 15, g4 = lane >> 4;

  // staging: thread t covers (row = t>>3, global k-chunk = (t&7)^(row&7))
  const int srow = tid >> 3;                          // 0..31
  const int scol = ((tid & 7) ^ (srow & 7)) * 8;      // element offset in k
  const f16* pA = A + (size_t)(brow * 128 + srow) * 768 + scol;
  const f16* pB = W + (size_t)(bcol * 128 + srow) * 768 + scol;
  char* ldsA = Asb + wid * 1024;  // + issue*4096 (wave-uniform, lane-linear)
  char* ldsB = Bsb + wid * 1024;

  const f32x4 zero4 = {0.f, 0.f, 0.f, 0.f};
  f32x4 acc[4][4];
#pragma unroll
  for (int i = 0; i < 4; ++i)
#pragma unroll
    for (int j = 0; j < 4; ++j) acc[i][j] = zero4;

  const int swz = (l15 & 7);
  for (int kt = 0; kt < KT; ++kt) {
#pragma unroll
    for (int i = 0; i < 4; ++i) {
      gload16(pA + (size_t)i * 32 * 768 + kt * 64, ldsA + i * 4096);
      gload16(pB + (size_t)i * 32 * 768 + kt * 64, ldsB + i * 4096);
    }
    __syncthreads();  // drains vmcnt -> staged tile visible
#pragma unroll
    for (int ks = 0; ks < 2; ++ks) {
      f16x8 af[4], bf[4];
#pragma unroll
      for (int f = 0; f < 4; ++f) {
        const int ra = wrow * 64 + f * 16 + l15;
        const int rb = wcol * 64 + f * 16 + l15;
        const int c = ((ks * 4 + g4) ^ swz) * 16;
        af[f] = *(const f16x8*)(Asb + ra * 128 + c);
        bf[f] = *(const f16x8*)(Bsb + rb * 128 + c);
      }
#pragma unroll
      for (int i = 0; i < 4; ++i)
#pragma unroll
        for (int j = 0; j < 4; ++j)
          acc[i][j] = MFMA16(af[i], bf[j], acc[i][j], 0, 0, 0);
    }
    __syncthreads();  // all reads done before next stage overwrites
  }

  // ---- epilogue ----
  if constexpr (MODE == 0) {
    const int s = bcol / 6;  // 0=q, 1=k, 2=v
#pragma unroll
    for (int i = 0; i < 4; ++i) {
#pragma unroll
      for (int r = 0; r < 4; ++r) {
        const int row = brow * 128 + wrow * 64 + i * 16 + g4 * 4 + r;
        const int bI = row / 196;
        const int nI = row - bI * 196;
#pragma unroll
        for (int j = 0; j < 4; ++j) {
          const int col = bcol * 128 + wcol * 64 + j * 16 + l15;
          const int rem = col - s * 768;
          const int hh = rem >> 6, dd = rem & 63;
          float v = acc[i][j][r];
          if (s == 0) {
            v = (v + bias_a[rem]) * 0.125f;
            q_out[(((size_t)bI * 12 + hh) * 196 + nI) * 64 + dd] = (f16)v;
          } else if (s == 1) {
            k_out[(((size_t)bI * 12 + hh) * 196 + nI) * 64 + dd] = (f16)v;
          } else {
            v += bias_b[rem];
            vT_out[(((size_t)bI * 12 + hh) * 64 + dd) * 224 + nI] = (f16)v;
          }
        }
      }
    }
  } else {
#pragma unroll
    for (int i = 0; i < 4; ++i) {
#pragma unroll
      for (int r = 0; r < 4; ++r) {
        const int row = brow * 128 + wrow * 64 + i * 16 + g4 * 4 + r;
        float* orow = f_out + (size_t)row * 768;
#pragma unroll
        for (int j = 0; j < 4; ++j) {
          const int col = bcol * 128 + wcol * 64 + j * 16 + l15;
          orow[col] = acc[i][j][r] + bias_a[col];
        }
      }
    }
  }
}

// ---------------- fused window attention: one WG (4 waves) per (b,h) -------------
__global__ __launch_bounds__(256) void attn_k(const f16* __restrict__ qg,
                                              const f16* __restrict__ kg,
                                              const f16* __restrict__ vTg,
                                              const f16* __restrict__ rpb,
                                              f16* __restrict__ og) {
  extern __shared__ char smem[];
  f16x8* Klds = (f16x8*)smem;              // [208 rows][8 chunks], swizzled
  f16x8* Vlds = (f16x8*)(smem + 26624);    // [64 d][32 m-chunks], swizzled
  f16x8* Plds = (f16x8*)(smem + 59392);    // 4 waves x [16 n][32 m-chunks]

  const int tid = threadIdx.x;
  const int bh = blockIdx.x;
  const int b = bh / 12, h = bh - b * 12;
  const int lane = tid & 63, wid = tid >> 6;
  const int l15 = lane & 15, g4 = lane >> 4;

  f16x8 z8;
#pragma unroll
  for (int j = 0; j < 8; ++j) z8[j] = (f16)0.f;

  const f16* kgb = kg + (size_t)bh * (196 * 64);
  for (int c = tid; c < 196 * 8; c += 256) {
    int m = c >> 3, dc = c & 7;
    Klds[m * 8 + (dc ^ (m & 7))] = *(const f16x8*)(kgb + m * 64 + dc * 8);
  }
  const f16* vgb = vTg + (size_t)bh * (64 * 224);
  for (int c = tid; c < 64 * 32; c += 256) {
    int d = c >> 5, mc = c & 31;
    f16x8 v;
    if (mc < 24) {
      v = *(const f16x8*)(vgb + d * 224 + mc * 8);
    } else if (mc == 24) {
      v = *(const f16x8*)(vgb + d * 224 + mc * 8);
#pragma unroll
      for (int j = 4; j < 8; ++j) v[j] = (f16)0.f;
    } else {
      v = z8;
    }
    Vlds[d * 32 + (mc ^ (d & 7))] = v;
  }
  f16x8* Pw = Plds + wid * (16 * 32);
  if (g4 < 2) {
    int n = l15;
    Pw[n * 32 + ((26 + g4) ^ (n & 7))] = z8;
  }
  __syncthreads();

  const f16* qgb = qg + (size_t)bh * (196 * 64);
  const f16* rpbh = rpb + (size_t)h * (196 * 196);

  for (int rt = wid; rt < 13; rt += 4) {
    const int n0 = rt * 16;
    f16x8 qf0 = *(const f16x8*)(qgb + (n0 + l15) * 64 + g4 * 8);
    f16x8 qf1 = *(const f16x8*)(qgb + (n0 + l15) * 64 + 32 + g4 * 8);

    float rv[13][4];
#pragma unroll
    for (int mt = 0; mt < 13; ++mt) {
      const int m = mt * 16 + l15;
      const int mcl = (m < 196) ? m : 195;
#pragma unroll
      for (int r = 0; r < 4; ++r) {
        const int n = n0 + g4 * 4 + r;
        const int ncl = (n < 196) ? n : 195;
        rv[mt][r] = (float)rpbh[ncl * 196 + mcl];
      }
    }

    const f32x4 zero4 = {0.f, 0.f, 0.f, 0.f};
    f32x4 s[13];
#pragma unroll
    for (int mt = 0; mt < 13; ++mt) {
      const int m = mt * 16 + l15;
      f16x8 k0 = Klds[m * 8 + ((g4) ^ (m & 7))];
      f16x8 k1 = Klds[m * 8 + ((4 + g4) ^ (m & 7))];
      s[mt] = MFMA16(qf0, k0, zero4, 0, 0, 0);
      s[mt] = MFMA16(qf1, k1, s[mt], 0, 0, 0);
    }

    float mx[4] = {-3e38f, -3e38f, -3e38f, -3e38f};
#pragma unroll
    for (int mt = 0; mt < 13; ++mt) {
      const int m = mt * 16 + l15;
#pragma unroll
      for (int r = 0; r < 4; ++r) {
        const int n = n0 + g4 * 4 + r;
        float v = (m < 196 && n < 196) ? s[mt][r] + rv[mt][r] : -1e30f;
        s[mt][r] = v;
        mx[r] = fmaxf(mx[r], v);
      }
    }
#pragma unroll
    for (int r = 0; r < 4; ++r) {
      mx[r] = fmaxf(mx[r], __shfl_xor(mx[r], 1));
      mx[r] = fmaxf(mx[r], __shfl_xor(mx[r], 2));
      mx[r] = fmaxf(mx[r], __shfl_xor(mx[r], 4));
      mx[r] = fmaxf(mx[r], __shfl_xor(mx[r], 8));
    }
    float sm[4] = {0.f, 0.f, 0.f, 0.f};
#pragma unroll
    for (int mt = 0; mt < 13; ++mt)
#pragma unroll
      for (int r = 0; r < 4; ++r) {
        float p = __expf(s[mt][r] - mx[r]);
        s[mt][r] = p;
        sm[r] += p;
      }
#pragma unroll
    for (int r = 0; r < 4; ++r) {
      sm[r] += __shfl_xor(sm[r], 1);
      sm[r] += __shfl_xor(sm[r], 2);
      sm[r] += __shfl_xor(sm[r], 4);
      sm[r] += __shfl_xor(sm[r], 8);
    }
    float rinv[4];
#pragma unroll
    for (int r = 0; r < 4; ++r) rinv[r] = 1.f / sm[r];

#pragma unroll
    for (int mt = 0; mt < 13; ++mt) {
      const int m = mt * 16 + l15;
#pragma unroll
      for (int r = 0; r < 4; ++r) {
        const int n = g4 * 4 + r;
        f16* dst = (f16*)Pw + n * 256 + (((m >> 3) ^ (n & 7)) << 3) + (m & 7);
        *dst = (f16)s[mt][r];
      }
    }

    f32x4 o[4];
#pragma unroll
    for (int dt = 0; dt < 4; ++dt) o[dt] = zero4;
#pragma unroll
    for (int ks = 0; ks < 7; ++ks) {
      f16x8 pa = Pw[l15 * 32 + ((ks * 4 + g4) ^ (l15 & 7))];
#pragma unroll
      for (int dt = 0; dt < 4; ++dt) {
        const int d = dt * 16 + l15;
        f16x8 vf = Vlds[d * 32 + ((ks * 4 + g4) ^ (d & 7))];
        o[dt] = MFMA16(pa, vf, o[dt], 0, 0, 0);
      }
    }

#pragma unroll
    for (int r = 0; r < 4; ++r) {
      const int n = n0 + g4 * 4 + r;
      if (n < 196) {
        f16* orow = og + ((size_t)b * 196 + n) * 768 + h * 64;
#pragma unroll
        for (int dt = 0; dt < 4; ++dt)
          orow[dt * 16 + l15] = (f16)(o[dt][r] * rinv[r]);
      }
    }
  }
}

// ------------------------------- launcher ---------------------------------------
extern "C" void kernel_launch(void* const* d_in, const int* in_sizes, int n_in,
                              void* d_out, int out_size, void* d_ws, size_t ws_size,
                              hipStream_t stream) {
  const float* x = (const float*)d_in[0];
  const float* qkv_w = (const float*)d_in[1];
  const float* q_bias = (const float*)d_in[2];
  const float* v_bias = (const float*)d_in[3];
  const float* rpb_tab = (const float*)d_in[4];
  const float* proj_w = (const float*)d_in[5];
  const float* proj_b = (const float*)d_in[6];
  const int* rel = (const int*)d_in[7];
  float* out = (float*)d_out;

  const size_t SZ_Q = 77070336;   // [3072][196][64] f16
  const size_t SZ_K = 77070336;
  const size_t SZ_VT = 88080384;  // [3072][64][224] f16
  const size_t SZ_AO = 77070336;  // [50176][768] f16 (also hosts xh before attn)
  const size_t SZ_RP = 921984;    // [12][196][196] f16
  const size_t SZ_WQ = 3538944;   // [2304][768] f16
  const size_t SZ_WP = 1179648;   // [768][768] f16
  if (ws_size < SZ_Q + SZ_K + SZ_VT + SZ_AO + SZ_RP + SZ_WQ + SZ_WP) return;

  char* w = (char*)d_ws;
  f16* q_ = (f16*)w;
  f16* k_ = (f16*)(w + SZ_Q);
  f16* vT_ = (f16*)(w + SZ_Q + SZ_K);
  f16* ao_ = (f16*)(w + SZ_Q + SZ_K + SZ_VT);
  f16* rp_ = (f16*)(w + SZ_Q + SZ_K + SZ_VT + SZ_AO);
  f16* whq_ = (f16*)(w + SZ_Q + SZ_K + SZ_VT + SZ_AO + SZ_RP);
  f16* whp_ = (f16*)(w + SZ_Q + SZ_K + SZ_VT + SZ_AO + SZ_RP + SZ_WQ);
  f16* xh_ = ao_;  // alias: xh dead before attn writes ao_

  (void)hipFuncSetAttribute((const void*)attn_k,
                            hipFuncAttributeMaxDynamicSharedMemorySize, 92160);

  cvt_k<<<2048, 256, 0, stream>>>(x, xh_, 50176 * 768 / 8);
  cvt_k<<<864, 256, 0, stream>>>(qkv_w, whq_, 2304 * 768 / 8);
  cvt_k<<<288, 256, 0, stream>>>(proj_w, whp_, 768 * 768 / 8);
  rpb_build_k<<<(196 * 196 + 255) / 256, 256, 0, stream>>>(rpb_tab, rel, rp_);

  gemm_k<0><<<392 * 18, 256, 0, stream>>>(xh_, whq_, q_bias, v_bias,
                                          q_, k_, vT_, nullptr);
  attn_k<<<3072, 256, 92160, stream>>>(q_, k_, vT_, rp_, ao_);
  gemm_k<1><<<392 * 6, 256, 0, stream>>>(ao_, whp_, proj_b, nullptr,
                                         nullptr, nullptr, nullptr, out);
}

// Round 3
// 778.325 us; speedup vs baseline: 1.4290x; 1.0568x over previous
//
#include <hip/hip_runtime.h>
#include <hip/hip_fp16.h>

typedef _Float16 f16;
typedef __attribute__((ext_vector_type(8))) _Float16 f16x8;
typedef __attribute__((ext_vector_type(4))) float f32x4;

#define MFMA16 __builtin_amdgcn_mfma_f32_16x16x32_f16
#define BAR() __builtin_amdgcn_s_barrier()
#define VMCNT(n) asm volatile("s_waitcnt vmcnt(" #n ")" ::: "memory")
#define LGKM(n) asm volatile("s_waitcnt lgkmcnt(" #n ")" ::: "memory")
#define SCHEDB() __builtin_amdgcn_sched_barrier(0)

__device__ __forceinline__ void gload16(const f16* g, char* l) {
  __builtin_amdgcn_global_load_lds(
      (const __attribute__((address_space(1))) void*)g,
      (__attribute__((address_space(3))) void*)l, 16, 0, 0);
}

// ---------------- fp32 -> fp16 bulk convert ----------------
__global__ __launch_bounds__(256) void cvt_k(const float* __restrict__ in,
                                             f16* __restrict__ out, int n8) {
  int i = blockIdx.x * 256 + threadIdx.x;
  const int stride = gridDim.x * 256;
  for (; i < n8; i += stride) {
    const float4* p = (const float4*)(in + (size_t)i * 8);
    float4 a = p[0], b = p[1];
    f16x8 h;
    h[0] = (f16)a.x; h[1] = (f16)a.y; h[2] = (f16)a.z; h[3] = (f16)a.w;
    h[4] = (f16)b.x; h[5] = (f16)b.y; h[6] = (f16)b.z; h[7] = (f16)b.w;
    *(f16x8*)(out + (size_t)i * 8) = h;
  }
}

// ---------------- rpb gather ----------------
__global__ __launch_bounds__(256) void rpb_build_k(const float* __restrict__ tab,
                                                   const int* __restrict__ rel,
                                                   f16* __restrict__ out) {
  int i = blockIdx.x * 256 + threadIdx.x;
  if (i >= 196 * 196) return;
  int idx = rel[i];
#pragma unroll
  for (int h = 0; h < 12; ++h)
    out[h * (196 * 196) + i] = (f16)tab[idx * 12 + h];
}

// ---------------- 256x256 8-phase GEMM: C = A[M,768] @ W[N,768]^T ----------------
// 512 thr / 8 waves (2Mx4N), BK=64, LDS 128KB dbuf, swizzled chunks, counted vmcnt.
// MODE 0: qkv epilogue (scatter q/k/vT f16). MODE 1: proj epilogue (f32 + bias).
template <int MODE>
__global__ __launch_bounds__(512) void gemm_k(
    const f16* __restrict__ A, const f16* __restrict__ W,
    const float* __restrict__ bias_a, const float* __restrict__ bias_b,
    f16* __restrict__ q_out, f16* __restrict__ k_out, f16* __restrict__ vT_out,
    float* __restrict__ f_out) {
  constexpr int NTIL = (MODE == 0) ? 9 : 3;     // 2304/256 or 768/256
  constexpr int NWG = (MODE == 0) ? 1764 : 588; // 196 * NTIL
  constexpr int QX = NWG / 8, RX = NWG % 8;
  constexpr int KT = 12;                        // 768/64

  extern __shared__ char lds[];  // [2 buf][A 32K | B 32K]; row = 64 f16 = 128B

  const int tid = threadIdx.x;
  const int lane = tid & 63, wid = tid >> 6;
  const int xcd = blockIdx.x & 7, bix = blockIdx.x >> 3;
  const int lbid =
      (xcd < RX ? xcd * (QX + 1) : RX * (QX + 1) + (xcd - RX) * QX) + bix;
  const int brow = lbid / NTIL, bcol = lbid % NTIL;
  const int wr = wid >> 2, wc = wid & 3;
  const int l15 = lane & 15, g4 = lane >> 4;

  // staging: thread covers rows sr, sr+64 of a 128-row half; swizzled k-chunk
  const int sr = wid * 8 + (lane >> 3);
  const int scw = ((lane & 7) ^ (lane >> 3)) * 8;
  const f16* pAt = A + (size_t)(brow * 256 + sr) * 768 + scw;
  const f16* pBt = W + (size_t)(bcol * 256 + sr) * 768 + scw;
  char* ldsW = lds + wid * 1024;  // wave-uniform; HW adds lane*16

  auto stA = [&](int kt, int hf, int buf) {
#pragma unroll
    for (int i = 0; i < 2; ++i)
      gload16(pAt + (size_t)(hf * 128 + i * 64) * 768 + kt * 64,
              ldsW + buf * 65536 + hf * 16384 + i * 8192);
  };
  auto stB = [&](int kt, int hf, int buf) {
#pragma unroll
    for (int i = 0; i < 2; ++i)
      gload16(pBt + (size_t)(hf * 128 + i * 64) * 768 + kt * 64,
              ldsW + buf * 65536 + 32768 + hf * 16384 + i * 8192);
  };

  f16x8 af[2][4][2], bf[2][2][2];
  const int aswz = l15 & 7;
  const char* ldsAl = lds + (size_t)(wr * 128 + l15) * 128;
  const char* ldsBl = lds + 32768 + (size_t)(wc * 64 + l15) * 128;

  auto rdA = [&](int q, int buf) {
#pragma unroll
    for (int mf = 0; mf < 4; ++mf)
#pragma unroll
      for (int ks = 0; ks < 2; ++ks)
        af[q][mf][ks] = *(const f16x8*)(ldsAl + buf * 65536 +
                                        (q * 64 + mf * 16) * 128 +
                                        ((ks * 4 + g4) ^ aswz) * 16);
  };
  auto rdB = [&](int r, int buf) {
#pragma unroll
    for (int nf = 0; nf < 2; ++nf)
#pragma unroll
      for (int ks = 0; ks < 2; ++ks)
        bf[r][nf][ks] = *(const f16x8*)(ldsBl + buf * 65536 +
                                        (r * 32 + nf * 16) * 128 +
                                        ((ks * 4 + g4) ^ aswz) * 16);
  };

  const f32x4 zero4 = {0.f, 0.f, 0.f, 0.f};
  f32x4 acc[8][4];
#pragma unroll
  for (int i = 0; i < 8; ++i)
#pragma unroll
    for (int j = 0; j < 4; ++j) acc[i][j] = zero4;

  auto mm = [&](int q, int r) {
#pragma unroll
    for (int ks = 0; ks < 2; ++ks)
#pragma unroll
      for (int mf = 0; mf < 4; ++mf)
#pragma unroll
        for (int nf = 0; nf < 2; ++nf)
          acc[q * 4 + mf][r * 2 + nf] =
              MFMA16(af[q][mf][ks], bf[r][nf][ks], acc[q * 4 + mf][r * 2 + nf],
                     0, 0, 0);
  };

  // prologue: tile0 fully + tile1 A-halves; wait tile0 landed (newest 4 may fly)
  stA(0, 0, 0); stA(0, 1, 0); stB(0, 0, 0); stB(0, 1, 0);
  stA(1, 0, 1); stA(1, 1, 1);
  VMCNT(4);
  BAR();

  for (int t = 0; t < KT; ++t) {
    const int cur = t & 1, nxt = cur ^ 1;
    // ph1: A(q0)+B(r0) reads | stage B0_{t+1} (other buf)
    rdA(0, cur); rdB(0, cur);
    if (t + 1 < KT) stB(t + 1, 0, nxt);
    LGKM(8);
    BAR(); LGKM(0); SCHEDB();
    __builtin_amdgcn_s_setprio(1); mm(0, 0); __builtin_amdgcn_s_setprio(0);
    BAR();
    // ph2: A(q1) reads | stage B1_{t+1} (other buf)
    rdA(1, cur);
    if (t + 1 < KT) stB(t + 1, 1, nxt);
    BAR(); LGKM(0); SCHEDB();
    __builtin_amdgcn_s_setprio(1); mm(1, 0); __builtin_amdgcn_s_setprio(0);
    BAR();
    // ph3: B(r1) reads | stage A0_{t+2} (cur buf; A0 consumed in ph1/ph2)
    rdB(1, cur);
    if (t + 2 < KT) stA(t + 2, 0, cur);
    BAR(); LGKM(0); SCHEDB();
    __builtin_amdgcn_s_setprio(1); mm(0, 1); __builtin_amdgcn_s_setprio(0);
    BAR();
    // ph4: stage A1_{t+2} (cur buf) | counted vmcnt once per K-tile
    if (t + 2 < KT) stA(t + 2, 1, cur);
    if (t < KT - 2) { VMCNT(4); } else if (t == KT - 2) { VMCNT(0); }
    BAR(); SCHEDB();
    __builtin_amdgcn_s_setprio(1); mm(1, 1); __builtin_amdgcn_s_setprio(0);
    BAR();
  }

  // ---- epilogue ----
#pragma unroll
  for (int mf = 0; mf < 8; ++mf) {
    const int rowo = wr * 128 + (mf >> 2) * 64 + (mf & 3) * 16 + g4 * 4;
#pragma unroll
    for (int rr = 0; rr < 4; ++rr) {
      const int grow = brow * 256 + rowo + rr;
      if constexpr (MODE == 0) {
        const int bI = grow / 196;
        const int nI = grow - bI * 196;
#pragma unroll
        for (int nf = 0; nf < 4; ++nf) {
          const int col = bcol * 256 + wc * 64 + (nf >> 1) * 32 + (nf & 1) * 16 + l15;
          const int s = bcol / 3;
          const int rem = col - s * 768;
          const int hh = rem >> 6, dd = rem & 63;
          float v = acc[mf][nf][rr];
          if (s == 0) {
            v = (v + bias_a[rem]) * 0.125f;
            q_out[(((size_t)bI * 12 + hh) * 196 + nI) * 64 + dd] = (f16)v;
          } else if (s == 1) {
            k_out[(((size_t)bI * 12 + hh) * 196 + nI) * 64 + dd] = (f16)v;
          } else {
            v += bias_b[rem];
            vT_out[(((size_t)bI * 12 + hh) * 64 + dd) * 224 + nI] = (f16)v;
          }
        }
      } else {
        float* orow = f_out + (size_t)grow * 768;
#pragma unroll
        for (int nf = 0; nf < 4; ++nf) {
          const int col = bcol * 256 + wc * 64 + (nf >> 1) * 32 + (nf & 1) * 16 + l15;
          orow[col] = acc[mf][nf][rr] + bias_a[col];
        }
      }
    }
  }
}

// ---------------- fused window attention: one WG (4 waves) per (b,h) -------------
__global__ __launch_bounds__(256) void attn_k(const f16* __restrict__ qg,
                                              const f16* __restrict__ kg,
                                              const f16* __restrict__ vTg,
                                              const f16* __restrict__ rpb,
                                              f16* __restrict__ og) {
  extern __shared__ char smem[];
  f16x8* Klds = (f16x8*)smem;              // [208 rows][8 chunks], swizzled
  f16x8* Vlds = (f16x8*)(smem + 26624);    // [64 d][32 m-chunks], swizzled
  f16x8* Plds = (f16x8*)(smem + 59392);    // 4 waves x [16 n][32 m-chunks]

  const int tid = threadIdx.x;
  const int bh = blockIdx.x;
  const int b = bh / 12, h = bh - b * 12;
  const int lane = tid & 63, wid = tid >> 6;
  const int l15 = lane & 15, g4 = lane >> 4;

  f16x8 z8;
#pragma unroll
  for (int j = 0; j < 8; ++j) z8[j] = (f16)0.f;

  const f16* kgb = kg + (size_t)bh * (196 * 64);
  for (int c = tid; c < 196 * 8; c += 256) {
    int m = c >> 3, dc = c & 7;
    Klds[m * 8 + (dc ^ (m & 7))] = *(const f16x8*)(kgb + m * 64 + dc * 8);
  }
  const f16* vgb = vTg + (size_t)bh * (64 * 224);
  for (int c = tid; c < 64 * 32; c += 256) {
    int d = c >> 5, mc = c & 31;
    f16x8 v;
    if (mc < 24) {
      v = *(const f16x8*)(vgb + d * 224 + mc * 8);
    } else if (mc == 24) {
      v = *(const f16x8*)(vgb + d * 224 + mc * 8);
#pragma unroll
      for (int j = 4; j < 8; ++j) v[j] = (f16)0.f;
    } else {
      v = z8;
    }
    Vlds[d * 32 + (mc ^ (d & 7))] = v;
  }
  f16x8* Pw = Plds + wid * (16 * 32);
  if (g4 < 2) {
    int n = l15;
    Pw[n * 32 + ((26 + g4) ^ (n & 7))] = z8;
  }
  __syncthreads();

  const f16* qgb = qg + (size_t)bh * (196 * 64);
  const f16* rpbh = rpb + (size_t)h * (196 * 196);

  for (int rt = wid; rt < 13; rt += 4) {
    const int n0 = rt * 16;
    f16x8 qf0 = *(const f16x8*)(qgb + (n0 + l15) * 64 + g4 * 8);
    f16x8 qf1 = *(const f16x8*)(qgb + (n0 + l15) * 64 + 32 + g4 * 8);

    float rv[13][4];
#pragma unroll
    for (int mt = 0; mt < 13; ++mt) {
      const int m = mt * 16 + l15;
      const int mcl = (m < 196) ? m : 195;
#pragma unroll
      for (int r = 0; r < 4; ++r) {
        const int n = n0 + g4 * 4 + r;
        const int ncl = (n < 196) ? n : 195;
        rv[mt][r] = (float)rpbh[ncl * 196 + mcl];
      }
    }

    const f32x4 zero4 = {0.f, 0.f, 0.f, 0.f};
    f32x4 s[13];
#pragma unroll
    for (int mt = 0; mt < 13; ++mt) {
      const int m = mt * 16 + l15;
      f16x8 k0 = Klds[m * 8 + ((g4) ^ (m & 7))];
      f16x8 k1 = Klds[m * 8 + ((4 + g4) ^ (m & 7))];
      s[mt] = MFMA16(qf0, k0, zero4, 0, 0, 0);
      s[mt] = MFMA16(qf1, k1, s[mt], 0, 0, 0);
    }

    float mx[4] = {-3e38f, -3e38f, -3e38f, -3e38f};
#pragma unroll
    for (int mt = 0; mt < 13; ++mt) {
      const int m = mt * 16 + l15;
#pragma unroll
      for (int r = 0; r < 4; ++r) {
        const int n = n0 + g4 * 4 + r;
        float v = (m < 196 && n < 196) ? s[mt][r] + rv[mt][r] : -1e30f;
        s[mt][r] = v;
        mx[r] = fmaxf(mx[r], v);
      }
    }
#pragma unroll
    for (int r = 0; r < 4; ++r) {
      mx[r] = fmaxf(mx[r], __shfl_xor(mx[r], 1));
      mx[r] = fmaxf(mx[r], __shfl_xor(mx[r], 2));
      mx[r] = fmaxf(mx[r], __shfl_xor(mx[r], 4));
      mx[r] = fmaxf(mx[r], __shfl_xor(mx[r], 8));
    }
    float sm[4] = {0.f, 0.f, 0.f, 0.f};
#pragma unroll
    for (int mt = 0; mt < 13; ++mt)
#pragma unroll
      for (int r = 0; r < 4; ++r) {
        float p = __expf(s[mt][r] - mx[r]);
        s[mt][r] = p;
        sm[r] += p;
      }
#pragma unroll
    for (int r = 0; r < 4; ++r) {
      sm[r] += __shfl_xor(sm[r], 1);
      sm[r] += __shfl_xor(sm[r], 2);
      sm[r] += __shfl_xor(sm[r], 4);
      sm[r] += __shfl_xor(sm[r], 8);
    }
    float rinv[4];
#pragma unroll
    for (int r = 0; r < 4; ++r) rinv[r] = 1.f / sm[r];

#pragma unroll
    for (int mt = 0; mt < 13; ++mt) {
      const int m = mt * 16 + l15;
#pragma unroll
      for (int r = 0; r < 4; ++r) {
        const int n = g4 * 4 + r;
        f16* dst = (f16*)Pw + n * 256 + (((m >> 3) ^ (n & 7)) << 3) + (m & 7);
        *dst = (f16)s[mt][r];
      }
    }

    f32x4 o[4];
#pragma unroll
    for (int dt = 0; dt < 4; ++dt) o[dt] = zero4;
#pragma unroll
    for (int ks = 0; ks < 7; ++ks) {
      f16x8 pa = Pw[l15 * 32 + ((ks * 4 + g4) ^ (l15 & 7))];
#pragma unroll
      for (int dt = 0; dt < 4; ++dt) {
        const int d = dt * 16 + l15;
        f16x8 vf = Vlds[d * 32 + ((ks * 4 + g4) ^ (d & 7))];
        o[dt] = MFMA16(pa, vf, o[dt], 0, 0, 0);
      }
    }

#pragma unroll
    for (int r = 0; r < 4; ++r) {
      const int n = n0 + g4 * 4 + r;
      if (n < 196) {
        f16* orow = og + ((size_t)b * 196 + n) * 768 + h * 64;
#pragma unroll
        for (int dt = 0; dt < 4; ++dt)
          orow[dt * 16 + l15] = (f16)(o[dt][r] * rinv[r]);
      }
    }
  }
}

// ------------------------------- launcher ---------------------------------------
extern "C" void kernel_launch(void* const* d_in, const int* in_sizes, int n_in,
                              void* d_out, int out_size, void* d_ws, size_t ws_size,
                              hipStream_t stream) {
  const float* x = (const float*)d_in[0];
  const float* qkv_w = (const float*)d_in[1];
  const float* q_bias = (const float*)d_in[2];
  const float* v_bias = (const float*)d_in[3];
  const float* rpb_tab = (const float*)d_in[4];
  const float* proj_w = (const float*)d_in[5];
  const float* proj_b = (const float*)d_in[6];
  const int* rel = (const int*)d_in[7];
  float* out = (float*)d_out;

  const size_t SZ_Q = 77070336;   // [3072][196][64] f16
  const size_t SZ_K = 77070336;
  const size_t SZ_VT = 88080384;  // [3072][64][224] f16
  const size_t SZ_AO = 77070336;  // [50176][768] f16 (also hosts xh before attn)
  const size_t SZ_RP = 921984;    // [12][196][196] f16
  const size_t SZ_WQ = 3538944;   // [2304][768] f16
  const size_t SZ_WP = 1179648;   // [768][768] f16
  if (ws_size < SZ_Q + SZ_K + SZ_VT + SZ_AO + SZ_RP + SZ_WQ + SZ_WP) return;

  char* w = (char*)d_ws;
  f16* q_ = (f16*)w;
  f16* k_ = (f16*)(w + SZ_Q);
  f16* vT_ = (f16*)(w + SZ_Q + SZ_K);
  f16* ao_ = (f16*)(w + SZ_Q + SZ_K + SZ_VT);
  f16* rp_ = (f16*)(w + SZ_Q + SZ_K + SZ_VT + SZ_AO);
  f16* whq_ = (f16*)(w + SZ_Q + SZ_K + SZ_VT + SZ_AO + SZ_RP);
  f16* whp_ = (f16*)(w + SZ_Q + SZ_K + SZ_VT + SZ_AO + SZ_RP + SZ_WQ);
  f16* xh_ = ao_;  // alias: xh dead before attn writes ao_

  (void)hipFuncSetAttribute((const void*)attn_k,
                            hipFuncAttributeMaxDynamicSharedMemorySize, 92160);
  (void)hipFuncSetAttribute((const void*)gemm_k<0>,
                            hipFuncAttributeMaxDynamicSharedMemorySize, 131072);
  (void)hipFuncSetAttribute((const void*)gemm_k<1>,
                            hipFuncAttributeMaxDynamicSharedMemorySize, 131072);

  cvt_k<<<2048, 256, 0, stream>>>(x, xh_, 50176 * 768 / 8);
  cvt_k<<<864, 256, 0, stream>>>(qkv_w, whq_, 2304 * 768 / 8);
  cvt_k<<<288, 256, 0, stream>>>(proj_w, whp_, 768 * 768 / 8);
  rpb_build_k<<<(196 * 196 + 255) / 256, 256, 0, stream>>>(rpb_tab, rel, rp_);

  gemm_k<0><<<1764, 512, 131072, stream>>>(xh_, whq_, q_bias, v_bias,
                                           q_, k_, vT_, nullptr);
  attn_k<<<3072, 256, 92160, stream>>>(q_, k_, vT_, rp_, ao_);
  gemm_k<1><<<588, 512, 131072, stream>>>(ao_, whp_, proj_b, nullptr,
                                          nullptr, nullptr, nullptr, out);
}

// Round 4
// 774.471 us; speedup vs baseline: 1.4361x; 1.0050x over previous
//
#include <hip/hip_runtime.h>
#include <hip/hip_fp16.h>

typedef _Float16 f16;
typedef __attribute__((ext_vector_type(8))) _Float16 f16x8;
typedef __attribute__((ext_vector_type(4))) float f32x4;

#define MFMA16 __builtin_amdgcn_mfma_f32_16x16x32_f16
#define BAR() __builtin_amdgcn_s_barrier()
#define VMCNT(n) asm volatile("s_waitcnt vmcnt(" #n ")" ::: "memory")
#define LGKM(n) asm volatile("s_waitcnt lgkmcnt(" #n ")" ::: "memory")
#define SCHEDB() __builtin_amdgcn_sched_barrier(0)

__device__ __forceinline__ void gload16(const f16* g, char* l) {
  __builtin_amdgcn_global_load_lds(
      (const __attribute__((address_space(1))) void*)g,
      (__attribute__((address_space(3))) void*)l, 16, 0, 0);
}

// ---------------- fp32 -> fp16 bulk convert ----------------
__global__ __launch_bounds__(256) void cvt_k(const float* __restrict__ in,
                                             f16* __restrict__ out, int n8) {
  int i = blockIdx.x * 256 + threadIdx.x;
  const int stride = gridDim.x * 256;
  for (; i < n8; i += stride) {
    const float4* p = (const float4*)(in + (size_t)i * 8);
    float4 a = p[0], b = p[1];
    f16x8 h;
    h[0] = (f16)a.x; h[1] = (f16)a.y; h[2] = (f16)a.z; h[3] = (f16)a.w;
    h[4] = (f16)b.x; h[5] = (f16)b.y; h[6] = (f16)b.z; h[7] = (f16)b.w;
    *(f16x8*)(out + (size_t)i * 8) = h;
  }
}

// ---------------- rpb gather ----------------
__global__ __launch_bounds__(256) void rpb_build_k(const float* __restrict__ tab,
                                                   const int* __restrict__ rel,
                                                   f16* __restrict__ out) {
  int i = blockIdx.x * 256 + threadIdx.x;
  if (i >= 196 * 196) return;
  int idx = rel[i];
#pragma unroll
  for (int h = 0; h < 12; ++h)
    out[h * (196 * 196) + i] = (f16)tab[idx * 12 + h];
}

// ---------------- 256x256 2-phase GEMM: C = A[M,768] @ W[N,768]^T ----------------
// 512 thr / 8 waves (2Mx4N), BK=64, LDS 128KB dbuf, swizzled chunks.
// T3-minimum schedule: stage-first, counted lgkm, ONE vmcnt(0)+barrier per K-tile.
template <int MODE>
__global__ __launch_bounds__(512) void gemm_k(
    const f16* __restrict__ A, const f16* __restrict__ W,
    const float* __restrict__ bias_a, const float* __restrict__ bias_b,
    f16* __restrict__ q_out, f16* __restrict__ k_out, f16* __restrict__ vT_out,
    float* __restrict__ f_out) {
  constexpr int NTIL = (MODE == 0) ? 9 : 3;     // 2304/256 or 768/256
  constexpr int NWG = 196 * NTIL;
  constexpr int QX = NWG / 8, RX = NWG % 8;
  constexpr int KT = 12;                        // 768/64

  extern __shared__ char lds[];  // [2 buf][A 32K | B 32K]; row = 64 f16 = 128B

  const int tid = threadIdx.x;
  const int lane = tid & 63, wid = tid >> 6;
  const int xcd = blockIdx.x & 7, bix = blockIdx.x >> 3;
  const int lbid =
      (xcd < RX ? xcd * (QX + 1) : RX * (QX + 1) + (xcd - RX) * QX) + bix;
  const int brow = lbid / NTIL, bcol = lbid % NTIL;
  const int wr = wid >> 2, wc = wid & 3;
  const int l15 = lane & 15, g4 = lane >> 4;

  // staging: thread covers row sr of each 64-row quarter; pre-swizzled k-chunk
  const int sr = wid * 8 + (lane >> 3);
  const int scw = ((lane & 7) ^ (lane >> 3)) * 8;
  const f16* pAt = A + (size_t)(brow * 256 + sr) * 768 + scw;
  const f16* pBt = W + (size_t)(bcol * 256 + sr) * 768 + scw;
  char* ldsW = lds + wid * 1024;  // wave-uniform; HW adds lane*16

  auto stA = [&](int kt, int hf, int buf) {
#pragma unroll
    for (int i = 0; i < 2; ++i)
      gload16(pAt + (size_t)(hf * 128 + i * 64) * 768 + kt * 64,
              ldsW + buf * 65536 + hf * 16384 + i * 8192);
  };
  auto stB = [&](int kt, int hf, int buf) {
#pragma unroll
    for (int i = 0; i < 2; ++i)
      gload16(pBt + (size_t)(hf * 128 + i * 64) * 768 + kt * 64,
              ldsW + buf * 65536 + 32768 + hf * 16384 + i * 8192);
  };

  f16x8 af[2][4][2], bf[2][2][2];
  const int aswz = l15 & 7;
  const char* ldsAl = lds + (size_t)(wr * 128 + l15) * 128;
  const char* ldsBl = lds + 32768 + (size_t)(wc * 64 + l15) * 128;

  auto rdA = [&](int q, int buf) {
#pragma unroll
    for (int mf = 0; mf < 4; ++mf)
#pragma unroll
      for (int ks = 0; ks < 2; ++ks)
        af[q][mf][ks] = *(const f16x8*)(ldsAl + buf * 65536 +
                                        (q * 64 + mf * 16) * 128 +
                                        ((ks * 4 + g4) ^ aswz) * 16);
  };
  auto rdB = [&](int r, int buf) {
#pragma unroll
    for (int nf = 0; nf < 2; ++nf)
#pragma unroll
      for (int ks = 0; ks < 2; ++ks)
        bf[r][nf][ks] = *(const f16x8*)(ldsBl + buf * 65536 +
                                        (r * 32 + nf * 16) * 128 +
                                        ((ks * 4 + g4) ^ aswz) * 16);
  };

  const f32x4 zero4 = {0.f, 0.f, 0.f, 0.f};
  f32x4 acc[8][4];
#pragma unroll
  for (int i = 0; i < 8; ++i)
#pragma unroll
    for (int j = 0; j < 4; ++j) acc[i][j] = zero4;

  auto mm = [&](int q, int r) {
#pragma unroll
    for (int ks = 0; ks < 2; ++ks)
#pragma unroll
      for (int mf = 0; mf < 4; ++mf)
#pragma unroll
        for (int nf = 0; nf < 2; ++nf)
          acc[q * 4 + mf][r * 2 + nf] =
              MFMA16(af[q][mf][ks], bf[r][nf][ks], acc[q * 4 + mf][r * 2 + nf],
                     0, 0, 0);
  };

  // prologue: stage tile 0
  stA(0, 0, 0); stA(0, 1, 0); stB(0, 0, 0); stB(0, 1, 0);
  VMCNT(0);
  BAR();

  for (int t = 0; t < KT; ++t) {
    const int cur = t & 1, nxt = cur ^ 1;
    // issue next tile's stage FIRST (latency hides under this tile's compute)
    if (t + 1 < KT) {
      stA(t + 1, 0, nxt); stA(t + 1, 1, nxt);
      stB(t + 1, 0, nxt); stB(t + 1, 1, nxt);
    }
    // first half reads (A-quad0 8 + B-pair0 4 = 12 ds_read_b128)
    rdA(0, cur); rdB(0, cur);
    SCHEDB();
    // second half reads (12 more)
    rdA(1, cur); rdB(1, cur);
    LGKM(12);  // first 12 landed
    SCHEDB();
    __builtin_amdgcn_s_setprio(1); mm(0, 0); mm(0, 1); __builtin_amdgcn_s_setprio(0);
    LGKM(0);
    SCHEDB();
    __builtin_amdgcn_s_setprio(1); mm(1, 0); mm(1, 1); __builtin_amdgcn_s_setprio(0);
    VMCNT(0);  // own stage-writes landed (issued ~full tile ago)
    BAR();     // everyone done reading cur + staged nxt
  }

  // ---- epilogue ----
#pragma unroll
  for (int mf = 0; mf < 8; ++mf) {
    const int rowo = wr * 128 + (mf >> 2) * 64 + (mf & 3) * 16 + g4 * 4;
#pragma unroll
    for (int rr = 0; rr < 4; ++rr) {
      const int grow = brow * 256 + rowo + rr;
      if constexpr (MODE == 0) {
        const int bI = grow / 196;
        const int nI = grow - bI * 196;
#pragma unroll
        for (int nf = 0; nf < 4; ++nf) {
          const int col = bcol * 256 + wc * 64 + (nf >> 1) * 32 + (nf & 1) * 16 + l15;
          const int s = bcol / 3;
          const int rem = col - s * 768;
          const int hh = rem >> 6, dd = rem & 63;
          float v = acc[mf][nf][rr];
          if (s == 0) {
            v = (v + bias_a[rem]) * 0.125f;
            q_out[(((size_t)bI * 12 + hh) * 196 + nI) * 64 + dd] = (f16)v;
          } else if (s == 1) {
            k_out[(((size_t)bI * 12 + hh) * 196 + nI) * 64 + dd] = (f16)v;
          } else {
            v += bias_b[rem];
            vT_out[(((size_t)bI * 12 + hh) * 64 + dd) * 224 + nI] = (f16)v;
          }
        }
      } else {
        float* orow = f_out + (size_t)grow * 768;
#pragma unroll
        for (int nf = 0; nf < 4; ++nf) {
          const int col = bcol * 256 + wc * 64 + (nf >> 1) * 32 + (nf & 1) * 16 + l15;
          orow[col] = acc[mf][nf][rr] + bias_a[col];
        }
      }
    }
  }
}

// ---------------- fused window attention: one WG (4 waves) per (b,h) -------------
// V + P in LDS (64KB -> 2 blocks/CU); K, Q, rpb direct from global (L1-resident).
__global__ __launch_bounds__(256) void attn_k(const f16* __restrict__ qg,
                                              const f16* __restrict__ kg,
                                              const f16* __restrict__ vTg,
                                              const f16* __restrict__ rpb,
                                              f16* __restrict__ og) {
  extern __shared__ char smem[];
  f16x8* Vlds = (f16x8*)smem;              // [64 d][32 m-chunks], swizzled
  f16x8* Plds = (f16x8*)(smem + 32768);    // 4 waves x [16 n][32 m-chunks]

  const int tid = threadIdx.x;
  const int bh = blockIdx.x;
  const int b = bh / 12, h = bh - b * 12;
  const int lane = tid & 63, wid = tid >> 6;
  const int l15 = lane & 15, g4 = lane >> 4;

  f16x8 z8;
#pragma unroll
  for (int j = 0; j < 8; ++j) z8[j] = (f16)0.f;

  // stage V^T [64][224] -> [d][mc ^ (d&7)], zero-fill m >= 196
  const f16* vgb = vTg + (size_t)bh * (64 * 224);
  for (int c = tid; c < 64 * 32; c += 256) {
    int d = c >> 5, mc = c & 31;
    f16x8 v;
    if (mc < 24) {
      v = *(const f16x8*)(vgb + d * 224 + mc * 8);
    } else if (mc == 24) {
      v = *(const f16x8*)(vgb + d * 224 + mc * 8);
#pragma unroll
      for (int j = 4; j < 8; ++j) v[j] = (f16)0.f;
    } else {
      v = z8;
    }
    Vlds[d * 32 + (mc ^ (d & 7))] = v;
  }
  // zero the P pad chunks that PV reads but softmax never writes (m in [208,224))
  f16x8* Pw = Plds + wid * (16 * 32);
  if (g4 < 2) {
    int n = l15;
    Pw[n * 32 + ((26 + g4) ^ (n & 7))] = z8;
  }
  __syncthreads();

  const f16* qgb = qg + (size_t)bh * (196 * 64);
  const f16* kgb = kg + (size_t)bh * (196 * 64);
  const f16* rpbh = rpb + (size_t)h * (196 * 196);

  for (int rt = wid; rt < 13; rt += 4) {
    const int n0 = rt * 16;
    f16x8 qf0 = *(const f16x8*)(qgb + (n0 + l15) * 64 + g4 * 8);
    f16x8 qf1 = *(const f16x8*)(qgb + (n0 + l15) * 64 + 32 + g4 * 8);

    float rv[13][4];
#pragma unroll
    for (int mt = 0; mt < 13; ++mt) {
      const int m = mt * 16 + l15;
      const int mcl = (m < 196) ? m : 195;
#pragma unroll
      for (int r = 0; r < 4; ++r) {
        const int n = n0 + g4 * 4 + r;
        const int ncl = (n < 196) ? n : 195;
        rv[mt][r] = (float)rpbh[ncl * 196 + mcl];
      }
    }

    // S = Q K^T ; K fragments direct from global (L1). Rows m>=196 read garbage
    // (within workspace); masked to -1e30 after (replace, not add -> NaN-safe).
    const f32x4 zero4 = {0.f, 0.f, 0.f, 0.f};
    f32x4 s[13];
#pragma unroll
    for (int mt = 0; mt < 13; ++mt) {
      const int m = mt * 16 + l15;
      f16x8 k0 = *(const f16x8*)(kgb + m * 64 + g4 * 8);
      f16x8 k1 = *(const f16x8*)(kgb + m * 64 + 32 + g4 * 8);
      s[mt] = MFMA16(qf0, k0, zero4, 0, 0, 0);
      s[mt] = MFMA16(qf1, k1, s[mt], 0, 0, 0);
    }

    float mx[4] = {-3e38f, -3e38f, -3e38f, -3e38f};
#pragma unroll
    for (int mt = 0; mt < 13; ++mt) {
      const int m = mt * 16 + l15;
#pragma unroll
      for (int r = 0; r < 4; ++r) {
        const int n = n0 + g4 * 4 + r;
        float v = (m < 196 && n < 196) ? s[mt][r] + rv[mt][r] : -1e30f;
        s[mt][r] = v;
        mx[r] = fmaxf(mx[r], v);
      }
    }
#pragma unroll
    for (int r = 0; r < 4; ++r) {
      mx[r] = fmaxf(mx[r], __shfl_xor(mx[r], 1));
      mx[r] = fmaxf(mx[r], __shfl_xor(mx[r], 2));
      mx[r] = fmaxf(mx[r], __shfl_xor(mx[r], 4));
      mx[r] = fmaxf(mx[r], __shfl_xor(mx[r], 8));
    }
    float sm[4] = {0.f, 0.f, 0.f, 0.f};
#pragma unroll
    for (int mt = 0; mt < 13; ++mt)
#pragma unroll
      for (int r = 0; r < 4; ++r) {
        float p = __expf(s[mt][r] - mx[r]);
        s[mt][r] = p;
        sm[r] += p;
      }
#pragma unroll
    for (int r = 0; r < 4; ++r) {
      sm[r] += __shfl_xor(sm[r], 1);
      sm[r] += __shfl_xor(sm[r], 2);
      sm[r] += __shfl_xor(sm[r], 4);
      sm[r] += __shfl_xor(sm[r], 8);
    }
    float rinv[4];
#pragma unroll
    for (int r = 0; r < 4; ++r) rinv[r] = 1.f / sm[r];

#pragma unroll
    for (int mt = 0; mt < 13; ++mt) {
      const int m = mt * 16 + l15;
#pragma unroll
      for (int r = 0; r < 4; ++r) {
        const int n = g4 * 4 + r;
        f16* dst = (f16*)Pw + n * 256 + (((m >> 3) ^ (n & 7)) << 3) + (m & 7);
        *dst = (f16)s[mt][r];
      }
    }

    f32x4 o[4];
#pragma unroll
    for (int dt = 0; dt < 4; ++dt) o[dt] = zero4;
#pragma unroll
    for (int ks = 0; ks < 7; ++ks) {
      f16x8 pa = Pw[l15 * 32 + ((ks * 4 + g4) ^ (l15 & 7))];
#pragma unroll
      for (int dt = 0; dt < 4; ++dt) {
        const int d = dt * 16 + l15;
        f16x8 vf = Vlds[d * 32 + ((ks * 4 + g4) ^ (d & 7))];
        o[dt] = MFMA16(pa, vf, o[dt], 0, 0, 0);
      }
    }

#pragma unroll
    for (int r = 0; r < 4; ++r) {
      const int n = n0 + g4 * 4 + r;
      if (n < 196) {
        f16* orow = og + ((size_t)b * 196 + n) * 768 + h * 64;
#pragma unroll
        for (int dt = 0; dt < 4; ++dt)
          orow[dt * 16 + l15] = (f16)(o[dt][r] * rinv[r]);
      }
    }
  }
}

// ------------------------------- launcher ---------------------------------------
extern "C" void kernel_launch(void* const* d_in, const int* in_sizes, int n_in,
                              void* d_out, int out_size, void* d_ws, size_t ws_size,
                              hipStream_t stream) {
  const float* x = (const float*)d_in[0];
  const float* qkv_w = (const float*)d_in[1];
  const float* q_bias = (const float*)d_in[2];
  const float* v_bias = (const float*)d_in[3];
  const float* rpb_tab = (const float*)d_in[4];
  const float* proj_w = (const float*)d_in[5];
  const float* proj_b = (const float*)d_in[6];
  const int* rel = (const int*)d_in[7];
  float* out = (float*)d_out;

  const size_t SZ_Q = 77070336;   // [3072][196][64] f16
  const size_t SZ_K = 77070336;
  const size_t SZ_VT = 88080384;  // [3072][64][224] f16
  const size_t SZ_AO = 77070336;  // [50176][768] f16 (also hosts xh before attn)
  const size_t SZ_RP = 921984;    // [12][196][196] f16
  const size_t SZ_WQ = 3538944;   // [2304][768] f16
  const size_t SZ_WP = 1179648;   // [768][768] f16
  if (ws_size < SZ_Q + SZ_K + SZ_VT + SZ_AO + SZ_RP + SZ_WQ + SZ_WP) return;

  char* w = (char*)d_ws;
  f16* q_ = (f16*)w;
  f16* k_ = (f16*)(w + SZ_Q);
  f16* vT_ = (f16*)(w + SZ_Q + SZ_K);
  f16* ao_ = (f16*)(w + SZ_Q + SZ_K + SZ_VT);
  f16* rp_ = (f16*)(w + SZ_Q + SZ_K + SZ_VT + SZ_AO);
  f16* whq_ = (f16*)(w + SZ_Q + SZ_K + SZ_VT + SZ_AO + SZ_RP);
  f16* whp_ = (f16*)(w + SZ_Q + SZ_K + SZ_VT + SZ_AO + SZ_RP + SZ_WQ);
  f16* xh_ = ao_;  // alias: xh dead before attn writes ao_

  (void)hipFuncSetAttribute((const void*)attn_k,
                            hipFuncAttributeMaxDynamicSharedMemorySize, 65536);
  (void)hipFuncSetAttribute((const void*)gemm_k<0>,
                            hipFuncAttributeMaxDynamicSharedMemorySize, 131072);
  (void)hipFuncSetAttribute((const void*)gemm_k<1>,
                            hipFuncAttributeMaxDynamicSharedMemorySize, 131072);

  cvt_k<<<2048, 256, 0, stream>>>(x, xh_, 50176 * 768 / 8);
  cvt_k<<<864, 256, 0, stream>>>(qkv_w, whq_, 2304 * 768 / 8);
  cvt_k<<<288, 256, 0, stream>>>(proj_w, whp_, 768 * 768 / 8);
  rpb_build_k<<<(196 * 196 + 255) / 256, 256, 0, stream>>>(rpb_tab, rel, rp_);

  gemm_k<0><<<1764, 512, 131072, stream>>>(xh_, whq_, q_bias, v_bias,
                                           q_, k_, vT_, nullptr);
  attn_k<<<3072, 256, 65536, stream>>>(q_, k_, vT_, rp_, ao_);
  gemm_k<1><<<588, 512, 131072, stream>>>(ao_, whp_, proj_b, nullptr,
                                          nullptr, nullptr, nullptr, out);
}